// Round 3
// baseline (330.331 us; speedup 1.0000x reference)
//
#include <hip/hip_runtime.h>
#include <stdint.h>

// ---------------------------------------------------------------------------
// PointWiseGate, round 8: kill the random ZT gather via counting sort.
//   k_init   : weight cvt + bucket/camax/hist init
//   k_corners: per-point bilinear offsets/weights + histogram(top-left hw)
//   k_zimg   : ZT[b][hw][m] = sum_c img[b][c][hw] * Wimg[m][c]
//   k_scan   : exclusive scan of hist (counting sort phase 2)
//   k_scatter: perm[rank] = point idx, rank by sorted corner location
//   k_blend  : sorted-order gather of ZT corners (sequential reads!),
//              blend -> write into Y rows (random full-line writes)
//   k_gemm1p : Y += Wpts . pts + bias (K=256 GEMM, coalesced epilogue),
//              BN partial stats
//   k_gate   : BN fin+apply+ReLU -> joint sa+ca1 -> sp -> ca2 -> atomicMax
//   k_out    : out = sigmoid(max+c2b) * sp * relu(bn(Y))
// ---------------------------------------------------------------------------

typedef __attribute__((ext_vector_type(8))) short bf16x8;
typedef __attribute__((ext_vector_type(4))) float f32x4;

#define B_ 4
#define N_ 16384
#define H_ 64
#define W_ 160
#define HW_ (H_ * W_)
#define K_ 512
#define NBIN_ (B_ * HW_)

__device__ __forceinline__ float bf2f(unsigned short u) {
    union { unsigned int i; float f; } c; c.i = ((unsigned int)u) << 16; return c.f;
}
__device__ __forceinline__ unsigned short f2bf(float f) {
    union { float f; unsigned int i; } c; c.f = f;
    unsigned int u = c.i;
    return (unsigned short)((u + 0x7FFFu + ((u >> 16) & 1u)) >> 16);
}
__device__ __forceinline__ unsigned int fkey(float f) {
    union { float f; unsigned int u; int i; } c; c.f = f;
    return (c.i < 0) ? ~c.u : (c.u | 0x80000000u);
}
__device__ __forceinline__ float funkey(unsigned int k) {
    union { unsigned int u; float f; } c;
    c.u = (k & 0x80000000u) ? (k & 0x7FFFFFFFu) : ~k;
    return c.f;
}

__device__ __forceinline__ void async_copy16(void* lds, const void* g) {
#if defined(__has_builtin) && __has_builtin(__builtin_amdgcn_global_load_lds)
    __builtin_amdgcn_global_load_lds(
        (const __attribute__((address_space(1))) unsigned int*)g,
        (__attribute__((address_space(3))) unsigned int*)lds, 16, 0, 0);
#else
    *(uint4*)lds = *(const uint4*)g;
#endif
}

// ---- weight cvt + workspace init (704 blocks)
__global__ __launch_bounds__(256) void k_init(const float* __restrict__ fw,
                                              const float* __restrict__ saw,
                                              const float* __restrict__ c1w,
                                              const float* __restrict__ c2w,
                                              unsigned short* WfB, unsigned short* saB,
                                              unsigned short* ca1B, unsigned short* ca2B,
                                              float* buckets, unsigned int* camax,
                                              unsigned int* hist) {
    int t = threadIdx.x;
    int j = blockIdx.x;
    if (j == 0) {
        for (int i = t; i < 16 * 512; i += 256) buckets[i] = 0.f;
        for (int i = t; i < 8 * 1024; i += 256) camax[i] = 0u;
    }
    if (j < 160) hist[j * 256 + t] = 0u;
    int i = j * 256 + t;
    if (i < 131072) WfB[i] = f2bf(fw[i]);
    else if (i < 147456) saB[i - 131072] = f2bf(saw[i - 131072]);
    else if (i < 163840) ca1B[i - 147456] = f2bf(c1w[i - 147456]);
    else if (i < 180224) ca2B[i - 163840] = f2bf(c2w[i - 163840]);
}

// ---- per-point bilinear corner offsets + weights + histogram (256 blocks)
__global__ __launch_bounds__(256) void k_corners(const float* __restrict__ pim,
                                                 uint4* __restrict__ offs4A,
                                                 float4* __restrict__ wts4A,
                                                 unsigned int* __restrict__ hist) {
    int idx = blockIdx.x * 256 + threadIdx.x;  // [0, 65536)
    float2 g2 = *(const float2*)(pim + (size_t)idx * 2);
    float x = (g2.x + 1.0f) * (0.5f * W_) - 0.5f;
    float y = (g2.y + 1.0f) * (0.5f * H_) - 0.5f;
    float xf = floorf(x), yf = floorf(y);
    float wx1 = x - xf, wx0 = 1.0f - wx1;
    float wy1 = y - yf, wy0 = 1.0f - wy1;
    int x0 = (int)xf, y0 = (int)yf;
    int x1 = x0 + 1, y1 = y0 + 1;
    float vx0 = (x0 >= 0 && x0 < W_) ? 1.f : 0.f;
    float vx1 = (x1 >= 0 && x1 < W_) ? 1.f : 0.f;
    float vy0 = (y0 >= 0 && y0 < H_) ? 1.f : 0.f;
    float vy1 = (y1 >= 0 && y1 < H_) ? 1.f : 0.f;
    int cx0 = min(max(x0, 0), W_ - 1), cx1 = min(max(x1, 0), W_ - 1);
    int cy0 = min(max(y0, 0), H_ - 1), cy1 = min(max(y1, 0), H_ - 1);
    uint4 o4;
    o4.x = (unsigned)(cy0 * W_ + cx0);
    o4.y = (unsigned)(cy0 * W_ + cx1);
    o4.z = (unsigned)(cy1 * W_ + cx0);
    o4.w = (unsigned)(cy1 * W_ + cx1);
    offs4A[idx] = o4;
    float4 w4;
    w4.x = wx0 * wy0 * vx0 * vy0;
    w4.y = wx1 * wy0 * vx1 * vy0;
    w4.z = wx0 * wy1 * vx0 * vy1;
    w4.w = wx1 * wy1 * vx1 * vy1;
    wts4A[idx] = w4;
    int b = idx >> 14;
    atomicAdd(&hist[b * HW_ + (int)o4.x], 1u);
}

// ---- exclusive scan of hist[NBIN_] -> binOfs (1 block, 256 threads)
__global__ __launch_bounds__(256) void k_scan(const unsigned int* __restrict__ hist,
                                              unsigned int* __restrict__ binOfs) {
    __shared__ unsigned int sums[256];
    int t = threadIdx.x;
    const int CH = NBIN_ / 256;  // 160
    unsigned int s = 0;
    for (int j = 0; j < CH; ++j) s += hist[t * CH + j];
    sums[t] = s;
    __syncthreads();
    for (int d = 1; d < 256; d <<= 1) {
        unsigned int v = (t >= d) ? sums[t - d] : 0u;
        __syncthreads();
        sums[t] += v;
        __syncthreads();
    }
    unsigned int base = (t == 0) ? 0u : sums[t - 1];
    for (int j = 0; j < CH; ++j) {
        unsigned int h = hist[t * CH + j];
        binOfs[t * CH + j] = base;
        base += h;
    }
}

// ---- counting-sort scatter: perm[rank] = idx (256 blocks)
__global__ __launch_bounds__(256) void k_scatter(const uint4* __restrict__ offs4A,
                                                 unsigned int* __restrict__ binOfs,
                                                 unsigned int* __restrict__ perm) {
    int idx = blockIdx.x * 256 + threadIdx.x;
    int b = idx >> 14;
    unsigned int key = offs4A[idx].x;
    unsigned int r = atomicAdd(&binOfs[b * HW_ + key], 1u);
    perm[r] = (unsigned int)idx;
}

// ---- ZT[b][hw][m] = sum_c img[b][c][hw] * Wimg[m][c]
// Block: 64 hw x 256 m, K=256 (8 k-tiles). Grid (160, 4).
__global__ __launch_bounds__(256, 3) void k_zimg(const unsigned short* __restrict__ WfB,
                                                 const float* __restrict__ img,
                                                 unsigned short* __restrict__ ZT) {
    __shared__ __align__(16) char smem[33792];
    unsigned short* At = (unsigned short*)smem;            // [256][32] 16384 B
    unsigned short* Bt = (unsigned short*)(smem + 16384);  // [64][40] 5120 B
    unsigned short* tile = (unsigned short*)smem;          // epi: [64][264] 33792 B

    int t = threadIdx.x;
    int hw0 = blockIdx.x * 64, b = blockIdx.y;
    int w = t >> 6, lane = t & 63, quad = lane >> 4, l15 = lane & 15;

    const f32x4 fzero = {0.f, 0.f, 0.f, 0.f};
    f32x4 acc[4][4];
#pragma unroll
    for (int i = 0; i < 4; ++i)
#pragma unroll
        for (int j = 0; j < 4; ++j) acc[i][j] = fzero;

    for (int kt = 0; kt < 8; ++kt) {
        int k0 = kt * 32;
        __syncthreads();
#pragma unroll
        for (int q = 0; q < 4; ++q) {
            int row = q * 64 + (t >> 2);
            async_copy16(At + (size_t)q * 2048 + (size_t)t * 8,
                         WfB + (size_t)row * K_ + k0 + (t & 3) * 8);
        }
        {
            int c_local = t & 31, g = t >> 5;
            int c = k0 + c_local;
            const float* src = img + ((size_t)b * 256 + c) * (size_t)HW_ + hw0 + g * 8;
            float4 v0 = *(const float4*)(src + 0);
            float4 v1 = *(const float4*)(src + 4);
            unsigned short* dst = Bt + (size_t)(g * 8) * 40 + c_local;
            dst[0 * 40] = f2bf(v0.x); dst[1 * 40] = f2bf(v0.y);
            dst[2 * 40] = f2bf(v0.z); dst[3 * 40] = f2bf(v0.w);
            dst[4 * 40] = f2bf(v1.x); dst[5 * 40] = f2bf(v1.y);
            dst[6 * 40] = f2bf(v1.z); dst[7 * 40] = f2bf(v1.w);
        }
        __syncthreads();
        bf16x8 af[4], bv[4];
#pragma unroll
        for (int j = 0; j < 4; ++j)
            bv[j] = *(const bf16x8*)(Bt + (j * 16 + l15) * 40 + quad * 8);
#pragma unroll
        for (int i = 0; i < 4; ++i)
            af[i] = *(const bf16x8*)(At + (w * 64 + i * 16 + l15) * 32 + quad * 8);
#pragma unroll
        for (int i = 0; i < 4; ++i)
#pragma unroll
            for (int j = 0; j < 4; ++j)
                acc[i][j] = __builtin_amdgcn_mfma_f32_16x16x32_bf16(af[i], bv[j], acc[i][j], 0, 0, 0);
    }

    // epilogue: LDS transpose tile -> coalesced 512B row stores
    __syncthreads();
#pragma unroll
    for (int i = 0; i < 4; ++i) {
        int m = w * 64 + i * 16 + quad * 4;
#pragma unroll
        for (int j = 0; j < 4; ++j) {
            int n = j * 16 + l15;
            ushort4 o;
            o.x = f2bf(acc[i][j][0]);
            o.y = f2bf(acc[i][j][1]);
            o.z = f2bf(acc[i][j][2]);
            o.w = f2bf(acc[i][j][3]);
            *(ushort4*)(tile + n * 264 + m) = o;
        }
    }
    __syncthreads();
    unsigned short* Zb = ZT + ((size_t)b * HW_ + hw0) * 256;
#pragma unroll
    for (int pass = 0; pass < 8; ++pass) {
        int row = pass * 8 + (t >> 5);
        int col = (t & 31) * 8;
        *(uint4*)(Zb + (size_t)row * 256 + col) = *(const uint4*)(tile + row * 264 + col);
    }
}

// ---- sorted blend: gather ZT corners in hw-sorted order, write into Y rows.
// 512 blocks x 256 threads; block handles ranks [bl*128, bl*128+128).
__global__ __launch_bounds__(256) void k_blend(const unsigned int* __restrict__ perm,
                                               const uint4* __restrict__ offs4A,
                                               const float4* __restrict__ wts4A,
                                               const unsigned short* __restrict__ ZT,
                                               unsigned short* __restrict__ Y) {
    int t = threadIdx.x;
    int bl = blockIdx.x;
    int q = t & 3;
#pragma unroll
    for (int p = 0; p < 2; ++p) {
        int rank = bl * 128 + p * 64 + (t >> 2);
        unsigned int idx = perm[rank];
        int b = (int)(idx >> 14), n = (int)(idx & 16383);
        uint4 o4 = offs4A[idx];
        float4 w4 = wts4A[idx];
        const unsigned short* Zb = ZT + (size_t)b * HW_ * 256;
        const unsigned short* pA = Zb + (size_t)o4.x * 256 + q * 64;
        const unsigned short* pB = Zb + (size_t)o4.y * 256 + q * 64;
        const unsigned short* pC = Zb + (size_t)o4.z * 256 + q * 64;
        const unsigned short* pD = Zb + (size_t)o4.w * 256 + q * 64;
        unsigned short* dst = Y + ((size_t)b * N_ + n) * 256 + q * 64;
#pragma unroll
        for (int s = 0; s < 8; ++s) {
            uint4 cA = *(const uint4*)(pA + s * 8);
            uint4 cB = *(const uint4*)(pB + s * 8);
            uint4 cC = *(const uint4*)(pC + s * 8);
            uint4 cD = *(const uint4*)(pD + s * 8);
            const unsigned short* qa = (const unsigned short*)&cA;
            const unsigned short* qb = (const unsigned short*)&cB;
            const unsigned short* qc = (const unsigned short*)&cC;
            const unsigned short* qd = (const unsigned short*)&cD;
            uint4 ov;
            unsigned short* po = (unsigned short*)&ov;
#pragma unroll
            for (int e = 0; e < 8; ++e)
                po[e] = f2bf(w4.x * bf2f(qa[e]) + w4.y * bf2f(qb[e]) +
                             w4.z * bf2f(qc[e]) + w4.w * bf2f(qd[e]));
            *(uint4*)(dst + s * 8) = ov;
        }
    }
}

// ---- main GEMM: Y[b][n][m] += Wpts[m][:].pts[b][:][n] + bias (Y pre-holds blend)
// Block: 256 m x 64 n, K=256 (8 k-tiles). Grid (256, 4) = 1024 blocks = 4/CU.
__global__ __launch_bounds__(256, 4) void k_gemm1p(const unsigned short* __restrict__ WfB,
                                                   const float* __restrict__ pts,
                                                   const float* __restrict__ fb,
                                                   unsigned short* __restrict__ Y,
                                                   float* __restrict__ buckets) {
    __shared__ __align__(16) char smem[36864];
    unsigned short* At = (unsigned short*)smem;                 // [256][32] 16384 B
    unsigned short* Bt = (unsigned short*)(smem + 16384);       // [64][40] 5120 B
    unsigned short* tile = (unsigned short*)smem;               // epi: [64][264] 33792 B
    float* biasS = (float*)(smem + 33792);                      // 1024 B
    float* redS  = (float*)(smem + 34816);                      // 1024 B
    float* redQ  = (float*)(smem + 35840);                      // 1024 B

    int t = threadIdx.x;
    int n0 = blockIdx.x * 64, bb = blockIdx.y;
    int w = t >> 6, lane = t & 63, quad = lane >> 4, l15 = lane & 15;

    biasS[t] = fb[t];

    const f32x4 fzero = {0.f, 0.f, 0.f, 0.f};
    f32x4 acc[4][4];
#pragma unroll
    for (int i = 0; i < 4; ++i)
#pragma unroll
        for (int j = 0; j < 4; ++j) acc[i][j] = fzero;

    for (int kt = 0; kt < 8; ++kt) {
        int k0 = kt * 32;
        __syncthreads();
        // A: Wpts rows m (cols 256.. of fw), async 16 B/lane
#pragma unroll
        for (int q = 0; q < 4; ++q) {
            int row = q * 64 + (t >> 2);
            async_copy16(At + (size_t)q * 2048 + (size_t)t * 8,
                         WfB + (size_t)row * K_ + 256 + k0 + (t & 3) * 8);
        }
        // B: pts fp32 coalesced load + LDS transpose (32 c x 64 n)
        {
            int c_local = t & 31, g = t >> 5;
            int c = k0 + c_local;
            const float* src = pts + ((size_t)bb * 256 + c) * (size_t)N_ + n0 + g * 8;
            float4 v0 = *(const float4*)(src + 0);
            float4 v1 = *(const float4*)(src + 4);
            unsigned short* dst = Bt + (size_t)(g * 8) * 40 + c_local;
            dst[0 * 40] = f2bf(v0.x); dst[1 * 40] = f2bf(v0.y);
            dst[2 * 40] = f2bf(v0.z); dst[3 * 40] = f2bf(v0.w);
            dst[4 * 40] = f2bf(v1.x); dst[5 * 40] = f2bf(v1.y);
            dst[6 * 40] = f2bf(v1.z); dst[7 * 40] = f2bf(v1.w);
        }
        __syncthreads();
        bf16x8 af[4], bv[4];
#pragma unroll
        for (int j = 0; j < 4; ++j)
            bv[j] = *(const bf16x8*)(Bt + (j * 16 + l15) * 40 + quad * 8);
#pragma unroll
        for (int i = 0; i < 4; ++i)
            af[i] = *(const bf16x8*)(At + (w * 64 + i * 16 + l15) * 32 + quad * 8);
#pragma unroll
        for (int i = 0; i < 4; ++i)
#pragma unroll
            for (int j = 0; j < 4; ++j)
                acc[i][j] = __builtin_amdgcn_mfma_f32_16x16x32_bf16(af[i], bv[j], acc[i][j], 0, 0, 0);
    }

    // ---- epilogue: coalesced Y-tile read (pre-blended img part), fold, store
    __syncthreads();  // all LDS reads of At/Bt done; tile may be overwritten

    size_t Yrow0 = ((size_t)bb * N_ + n0) * 256;
#pragma unroll
    for (int pass = 0; pass < 8; ++pass) {
        int row = pass * 8 + (t >> 5);
        int col = (t & 31) * 8;
        *(uint4*)(tile + row * 264 + col) = *(const uint4*)(Y + Yrow0 + (size_t)row * 256 + col);
    }
    __syncthreads();
    // fold pass: every wave folds acc+bias into its m-range, BN stats
#pragma unroll
    for (int i = 0; i < 4; ++i) {
        int mloc = w * 64 + i * 16 + quad * 4;
        float b0 = biasS[mloc + 0], b1 = biasS[mloc + 1];
        float b2 = biasS[mloc + 2], b3 = biasS[mloc + 3];
        float s0 = 0.f, q0 = 0.f, s1 = 0.f, q1 = 0.f;
        float s2 = 0.f, q2 = 0.f, s3 = 0.f, q3 = 0.f;
#pragma unroll
        for (int j = 0; j < 4; ++j) {
            int n = j * 16 + l15;
            ushort4 v = *(const ushort4*)(tile + n * 264 + mloc);
            float y0 = acc[i][j][0] + bf2f(v.x) + b0;
            float y1 = acc[i][j][1] + bf2f(v.y) + b1;
            float y2 = acc[i][j][2] + bf2f(v.z) + b2;
            float y3 = acc[i][j][3] + bf2f(v.w) + b3;
            s0 += y0; q0 += y0 * y0;
            s1 += y1; q1 += y1 * y1;
            s2 += y2; q2 += y2 * y2;
            s3 += y3; q3 += y3 * y3;
            ushort4 o;
            o.x = f2bf(y0); o.y = f2bf(y1); o.z = f2bf(y2); o.w = f2bf(y3);
            *(ushort4*)(tile + n * 264 + mloc) = o;
        }
#pragma unroll
        for (int d = 1; d < 16; d <<= 1) {
            s0 += __shfl_xor(s0, d, 64); q0 += __shfl_xor(q0, d, 64);
            s1 += __shfl_xor(s1, d, 64); q1 += __shfl_xor(q1, d, 64);
            s2 += __shfl_xor(s2, d, 64); q2 += __shfl_xor(q2, d, 64);
            s3 += __shfl_xor(s3, d, 64); q3 += __shfl_xor(q3, d, 64);
        }
        if (l15 == 0) {
            redS[mloc + 0] = s0; redQ[mloc + 0] = q0;
            redS[mloc + 1] = s1; redQ[mloc + 1] = q1;
            redS[mloc + 2] = s2; redQ[mloc + 2] = q2;
            redS[mloc + 3] = s3; redQ[mloc + 3] = q3;
        }
    }
    __syncthreads();
    {
        float* bk = buckets + (size_t)(blockIdx.x & 15) * 512;
        atomicAdd(bk + t, redS[t]);
        atomicAdd(bk + 256 + t, redQ[t]);
    }
#pragma unroll
    for (int pass = 0; pass < 8; ++pass) {
        int row = pass * 8 + (t >> 5);
        int col = (t & 31) * 8;
        *(uint4*)(Y + Yrow0 + (size_t)row * 256 + col) = *(const uint4*)(tile + row * 264 + col);
    }
}

// ---- fused gate (unchanged)
__global__ __launch_bounds__(256, 2) void k_gate(const unsigned short* __restrict__ Y,
                                                 const float* __restrict__ buckets,
                                                 const float* __restrict__ gamma,
                                                 const float* __restrict__ beta,
                                                 const unsigned short* __restrict__ saB,
                                                 const float* __restrict__ sab,
                                                 const unsigned short* __restrict__ c1B,
                                                 const float* __restrict__ c1b,
                                                 const unsigned short* __restrict__ c2B,
                                                 unsigned int* __restrict__ camax,
                                                 float* __restrict__ sp_g,
                                                 float* __restrict__ ss_out) {
    __shared__ __align__(16) unsigned short Ft[64 * 264];
    __shared__ __align__(16) unsigned short Ht[64 * 72];
    __shared__ float scS[256], shS[256];
    __shared__ float saPart[4][64];
    __shared__ float spL[64];
    int t = threadIdx.x;
    size_t pts0 = (size_t)blockIdx.x * 64;
    int b = (int)(pts0 >> 14);
    int w = t >> 6, lane = t & 63, quad = lane >> 4, l15 = lane & 15;
    int jrow = w * 16 + l15;

    bf16x8 bvs[8], bvc[8];
#pragma unroll
    for (int kt = 0; kt < 8; ++kt) {
        bvs[kt] = *(const bf16x8*)(saB + (size_t)jrow * 256 + kt * 32 + quad * 8);
        bvc[kt] = *(const bf16x8*)(c1B + (size_t)jrow * 256 + kt * 32 + quad * 8);
    }
    float sbias = sab[jrow];
    float cbias = c1b[jrow];

    {
        float s = 0.f, q = 0.f;
#pragma unroll
        for (int bk = 0; bk < 16; ++bk) {
            s += buckets[bk * 512 + t];
            q += buckets[bk * 512 + 256 + t];
        }
        const float inv = 1.0f / (float)(B_ * N_);
        float mean = s * inv;
        float var = q * inv - mean * mean;
        float sc = gamma[t] * rsqrtf(var + 1e-5f);
        float sh = beta[t] - mean * sc;
        scS[t] = sc;
        shS[t] = sh;
        if (blockIdx.x == 0) { ss_out[t] = sc; ss_out[256 + t] = sh; }
    }
    __syncthreads();

    int cc = (t * 8) & 255;
    float scr[8], shr[8];
#pragma unroll
    for (int e = 0; e < 8; ++e) { scr[e] = scS[cc + e]; shr[e] = shS[cc + e]; }
    for (int idx = t * 8; idx < 64 * 256; idx += 2048) {
        int r = idx >> 8;
        uint4 v = *(const uint4*)(Y + (pts0 + r) * 256 + cc);
        unsigned short* us = (unsigned short*)&v;
#pragma unroll
        for (int e = 0; e < 8; ++e) {
            float f = bf2f(us[e]) * scr[e] + shr[e];
            us[e] = f2bf(fmaxf(f, 0.f));
        }
        *(uint4*)(Ft + r * 264 + cc) = v;
    }
    __syncthreads();

    const f32x4 fzero = {0.f, 0.f, 0.f, 0.f};
    f32x4 accS[4], accC[4];
#pragma unroll
    for (int i = 0; i < 4; ++i) { accS[i] = fzero; accC[i] = fzero; }
#pragma unroll
    for (int kt = 0; kt < 8; ++kt) {
        bf16x8 af[4];
#pragma unroll
        for (int i = 0; i < 4; ++i)
            af[i] = *(const bf16x8*)(Ft + (i * 16 + l15) * 264 + kt * 32 + quad * 8);
#pragma unroll
        for (int i = 0; i < 4; ++i) {
            accS[i] = __builtin_amdgcn_mfma_f32_16x16x32_bf16(af[i], bvs[kt], accS[i], 0, 0, 0);
            accC[i] = __builtin_amdgcn_mfma_f32_16x16x32_bf16(af[i], bvc[kt], accC[i], 0, 0, 0);
        }
    }
#pragma unroll
    for (int i = 0; i < 4; ++i) {
#pragma unroll
        for (int r = 0; r < 4; ++r) {
            float v = accS[i][r] + sbias;
#pragma unroll
            for (int d = 1; d < 16; d <<= 1) v = fmaxf(v, __shfl_xor(v, d, 64));
            if (l15 == 0) saPart[w][i * 16 + quad * 4 + r] = v;
        }
    }
    __syncthreads();
    if (t < 64) {
        float m4 = fmaxf(fmaxf(saPart[0][t], saPart[1][t]),
                         fmaxf(saPart[2][t], saPart[3][t]));
        float sv = 1.0f / (1.0f + __expf(-m4));
        spL[t] = sv;
        sp_g[pts0 + t] = sv;
    }
    __syncthreads();

#pragma unroll
    for (int i = 0; i < 4; ++i) {
#pragma unroll
        for (int r = 0; r < 4; ++r) {
            int pt = i * 16 + quad * 4 + r;
            float hv = fmaxf(accC[i][r] * spL[pt] + cbias, 0.f);
            Ht[pt * 72 + jrow] = f2bf(hv);
        }
    }
    __syncthreads();

    {
        bf16x8 b2a[4], b2b[4];
#pragma unroll
        for (int mt = 0; mt < 4; ++mt) {
            b2a[mt] = *(const bf16x8*)(c2B + (size_t)(w * 64 + mt * 16 + l15) * 64 + quad * 8);
            b2b[mt] = *(const bf16x8*)(c2B + (size_t)(w * 64 + mt * 16 + l15) * 64 + 32 + quad * 8);
        }
        float vmax[4] = {-3e38f, -3e38f, -3e38f, -3e38f};
#pragma unroll
        for (int i = 0; i < 4; ++i) {
            bf16x8 a0 = *(const bf16x8*)(Ht + (i * 16 + l15) * 72 + quad * 8);
            bf16x8 a1 = *(const bf16x8*)(Ht + (i * 16 + l15) * 72 + 32 + quad * 8);
#pragma unroll
            for (int mt = 0; mt < 4; ++mt) {
                f32x4 acc = __builtin_amdgcn_mfma_f32_16x16x32_bf16(a0, b2a[mt], fzero, 0, 0, 0);
                acc = __builtin_amdgcn_mfma_f32_16x16x32_bf16(a1, b2b[mt], acc, 0, 0, 0);
#pragma unroll
                for (int r = 0; r < 4; ++r) vmax[mt] = fmaxf(vmax[mt], acc[r]);
            }
        }
        unsigned int* cam = camax + (size_t)(blockIdx.x & 7) * 1024 + b * 256;
#pragma unroll
        for (int mt = 0; mt < 4; ++mt) {
            float v = vmax[mt];
            v = fmaxf(v, __shfl_xor(v, 16, 64));
            v = fmaxf(v, __shfl_xor(v, 32, 64));
            if (quad == 0) atomicMax(cam + w * 64 + mt * 16 + l15, fkey(v));
        }
    }
}

// ---- out (unchanged)
__global__ __launch_bounds__(256) void k_out(const unsigned short* __restrict__ Y,
                                             const unsigned int* __restrict__ camax,
                                             const float* __restrict__ c2b,
                                             const float* __restrict__ ss,
                                             const float* __restrict__ sp_g,
                                             float* __restrict__ out) {
    __shared__ __align__(16) unsigned short tile[64 * 68];
    __shared__ float ch[64], scT[64], shT[64], spT[64];
    int t = threadIdx.x;
    int n0 = blockIdx.x * 64, m0 = blockIdx.y * 64, b = blockIdx.z;
    if (t < 64) {
        int m = m0 + t;
        unsigned int k = 0u;
#pragma unroll
        for (int bk = 0; bk < 8; ++bk) k = max(k, camax[bk * 1024 + b * 256 + m]);
        ch[t] = 1.0f / (1.0f + __expf(-(funkey(k) + c2b[m])));
        scT[t] = ss[m];
        shT[t] = ss[256 + m];
        spT[t] = sp_g[(size_t)b * N_ + n0 + t];
    }
    int sub = (t & 15) * 4, grp = t >> 4;
    const unsigned short* src = Y + ((size_t)b * N_ + n0) * 256 + m0;
#pragma unroll
    for (int it = 0; it < 4; ++it) {
        int nl = grp + it * 16;
        ushort4 v = *(const ushort4*)(src + (size_t)nl * 256 + sub);
        *(ushort4*)(tile + nl * 68 + sub) = v;
    }
    __syncthreads();
    float* dst = out + ((size_t)b * 256 + m0) * N_ + n0;
#pragma unroll
    for (int it = 0; it < 4; ++it) {
        int ml = grp + it * 16;
        float g = ch[ml], scv = scT[ml], shv = shT[ml];
        float4 o;
        o.x = fmaxf(bf2f(tile[(sub + 0) * 68 + ml]) * scv + shv, 0.f) * spT[sub + 0] * g;
        o.y = fmaxf(bf2f(tile[(sub + 1) * 68 + ml]) * scv + shv, 0.f) * spT[sub + 1] * g;
        o.z = fmaxf(bf2f(tile[(sub + 2) * 68 + ml]) * scv + shv, 0.f) * spT[sub + 2] * g;
        o.w = fmaxf(bf2f(tile[(sub + 3) * 68 + ml]) * scv + shv, 0.f) * spT[sub + 3] * g;
        *(float4*)(dst + (size_t)ml * N_ + sub) = o;
    }
}

extern "C" void kernel_launch(void* const* d_in, const int* in_sizes, int n_in,
                              void* d_out, int out_size, void* d_ws, size_t ws_size,
                              hipStream_t stream) {
    (void)in_sizes; (void)n_in; (void)out_size; (void)ws_size;
    const float* pts_img = (const float*)d_in[0];
    const float* img     = (const float*)d_in[1];
    const float* pts     = (const float*)d_in[2];
    const float* fw      = (const float*)d_in[3];
    const float* fbias   = (const float*)d_in[4];
    const float* gamma   = (const float*)d_in[5];
    const float* beta    = (const float*)d_in[6];
    const float* c1w     = (const float*)d_in[7];
    const float* c1b     = (const float*)d_in[8];
    const float* c2w     = (const float*)d_in[9];
    const float* c2b     = (const float*)d_in[10];
    const float* saw     = (const float*)d_in[11];
    const float* sab     = (const float*)d_in[12];
    float* out = (float*)d_out;

    char* ws = (char*)d_ws;
    unsigned short* ZT   = (unsigned short*)(ws);              // 20,971,520 B
    unsigned short* Y    = (unsigned short*)(ws + 20971520);   // 33,554,432 B
    unsigned short* WfB  = (unsigned short*)(ws + 54525952);   // 262,144 B
    unsigned short* saB  = (unsigned short*)(ws + 54788096);   // 32,768 B
    unsigned short* ca1B = (unsigned short*)(ws + 54820864);   // 32,768 B
    unsigned short* ca2B = (unsigned short*)(ws + 54853632);   // 32,768 B
    float* buckets       = (float*)(ws + 54886400);            // 32,768 B
    unsigned int* camax  = (unsigned int*)(ws + 54919168);     // 32,768 B
    float* sp_g          = (float*)(ws + 54951936);            // 262,144 B
    float* ss            = (float*)(ws + 55214080);            // 2,048 B
    uint4* offs4A        = (uint4*)(ws + 55216128);            // 1,048,576 B
    float4* wts4A        = (float4*)(ws + 56264704);           // 1,048,576 B
    unsigned int* hist   = (unsigned int*)(ws + 57313280);     // 163,840 B
    unsigned int* binOfs = (unsigned int*)(ws + 57477120);     // 163,840 B
    unsigned int* perm   = (unsigned int*)(ws + 57640960);     // 262,144 B

    k_init<<<704, 256, 0, stream>>>(fw, saw, c1w, c2w, WfB, saB, ca1B, ca2B,
                                    buckets, camax, hist);
    k_corners<<<256, 256, 0, stream>>>(pts_img, offs4A, wts4A, hist);
    k_zimg<<<dim3(160, 4), 256, 0, stream>>>(WfB, img, ZT);
    k_scan<<<1, 256, 0, stream>>>(hist, binOfs);
    k_scatter<<<256, 256, 0, stream>>>(offs4A, binOfs, perm);
    k_blend<<<512, 256, 0, stream>>>(perm, offs4A, wts4A, ZT, Y);
    k_gemm1p<<<dim3(256, 4), 256, 0, stream>>>(WfB, pts, fbias, Y, buckets);
    k_gate<<<1024, 256, 0, stream>>>(Y, buckets, gamma, beta, saB, sab, ca1B, c1b,
                                     ca2B, camax, sp_g, ss);
    k_out<<<dim3(256, 4, 4), 256, 0, stream>>>(Y, camax, c2b, ss, sp_g, out);
}

// Round 4
// 248.432 us; speedup vs baseline: 1.3297x; 1.3297x over previous
//
#include <hip/hip_runtime.h>
#include <stdint.h>

// ---------------------------------------------------------------------------
// PointWiseGate, round 9: R0 champion structure, occupancy-fixed gemm1f.
//   k_imgt  : img -> imgT (B,HW,256) bf16  [+ weight cvt + init, folded]
//   k_gemm1f: fused GEMM1 (K=512), B staged on the fly:
//               K[0,256)  = bilinear gather from imgT (k-sliced -> L2-resident)
//               K[256,512)= fp32 pts load + LDS transpose
//             n-tile 64 -> grid (256,4) = 4 blocks/CU (was 2: latency-bound)
//   k_gate  : BN fin+apply+ReLU -> joint sa+ca1 -> sp -> ca2 -> atomicMax
//   k_out   : out = sigmoid(max+c2b) * sp * relu(bn(Y))
// ---------------------------------------------------------------------------

typedef __attribute__((ext_vector_type(8))) short bf16x8;
typedef __attribute__((ext_vector_type(4))) float f32x4;

#define B_ 4
#define N_ 16384
#define H_ 64
#define W_ 160
#define HW_ (H_ * W_)
#define K_ 512

__device__ __forceinline__ float bf2f(unsigned short u) {
    union { unsigned int i; float f; } c; c.i = ((unsigned int)u) << 16; return c.f;
}
__device__ __forceinline__ unsigned short f2bf(float f) {
    union { float f; unsigned int i; } c; c.f = f;
    unsigned int u = c.i;
    return (unsigned short)((u + 0x7FFFu + ((u >> 16) & 1u)) >> 16);
}
__device__ __forceinline__ unsigned int fkey(float f) {
    union { float f; unsigned int u; int i; } c; c.f = f;
    return (c.i < 0) ? ~c.u : (c.u | 0x80000000u);
}
__device__ __forceinline__ float funkey(unsigned int k) {
    union { unsigned int u; float f; } c;
    c.u = (k & 0x80000000u) ? (k & 0x7FFFFFFFu) : ~k;
    return c.f;
}

__device__ __forceinline__ void async_copy16(void* lds, const void* g) {
#if defined(__has_builtin) && __has_builtin(__builtin_amdgcn_global_load_lds)
    __builtin_amdgcn_global_load_lds(
        (const __attribute__((address_space(1))) unsigned int*)g,
        (__attribute__((address_space(3))) unsigned int*)lds, 16, 0, 0);
#else
    *(uint4*)lds = *(const uint4*)g;
#endif
}

// ---- img transpose + weight cvt + init (1D grid: 2560 transpose + 704 weights)
__global__ __launch_bounds__(256) void k_imgt(const float* __restrict__ img,
                                              unsigned short* __restrict__ imgT,
                                              const float* __restrict__ fw,
                                              const float* __restrict__ saw,
                                              const float* __restrict__ c1w,
                                              const float* __restrict__ c2w,
                                              unsigned short* WfB, unsigned short* saB,
                                              unsigned short* ca1B, unsigned short* ca2B,
                                              float* buckets, unsigned int* camax) {
    int t = threadIdx.x;
    int bx = blockIdx.x;
    if (bx < 2560) {
        __shared__ __align__(16) unsigned short tile[64 * 68];
        int hw0 = (bx % 160) * 64, c0 = ((bx / 160) & 3) * 64, b = bx / 640;
        const float* src = img + ((size_t)b * 256 + c0) * HW_ + hw0;
        int sub = (t & 15) * 4, grp = t >> 4;
#pragma unroll
        for (int it = 0; it < 4; ++it) {
            int cl = grp + it * 16;
            float4 v = *(const float4*)(src + (size_t)cl * HW_ + sub);
            ushort4 o;
            o.x = f2bf(v.x); o.y = f2bf(v.y); o.z = f2bf(v.z); o.w = f2bf(v.w);
            *(ushort4*)(tile + cl * 68 + sub) = o;
        }
        __syncthreads();
        unsigned short* dst = imgT + ((size_t)b * HW_ + hw0) * 256 + c0;
#pragma unroll
        for (int it = 0; it < 4; ++it) {
            int hwl = grp + it * 16;
            ushort4 o;
            o.x = tile[(sub + 0) * 68 + hwl];
            o.y = tile[(sub + 1) * 68 + hwl];
            o.z = tile[(sub + 2) * 68 + hwl];
            o.w = tile[(sub + 3) * 68 + hwl];
            *(ushort4*)(dst + (size_t)hwl * 256 + sub) = o;
        }
    } else {
        int j = bx - 2560;
        if (j == 0) {
            for (int i = t; i < 16 * 512; i += 256) buckets[i] = 0.f;
            for (int i = t; i < 8 * 1024; i += 256) camax[i] = 0u;
        }
        int i = j * 256 + t;
        if (i < 131072) WfB[i] = f2bf(fw[i]);
        else if (i < 147456) saB[i - 131072] = f2bf(saw[i - 131072]);
        else if (i < 163840) ca1B[i - 147456] = f2bf(c1w[i - 147456]);
        else if (i < 180224) ca2B[i - 163840] = f2bf(c2w[i - 163840]);
    }
}

// ---- fused GEMM1: Y[b][n][m] = Wf[m][:].X[b][n][:] + bias; X staged on the fly.
// Block: full M=256 x 64 n. Grid (256,4) = 1024 blocks = 4/CU. acc[4][4].
__global__ __launch_bounds__(256, 4) void k_gemm1f(const unsigned short* __restrict__ WfB,
                                                   const float* __restrict__ pim,
                                                   const unsigned short* __restrict__ imgT,
                                                   const float* __restrict__ pts,
                                                   const float* __restrict__ fb,
                                                   unsigned short* __restrict__ Y,
                                                   float* __restrict__ buckets) {
    __shared__ __align__(16) char smem[38912];
    unsigned short* At = (unsigned short*)smem;                 // [256][32] 16384 B
    unsigned short* Bt = (unsigned short*)(smem + 16384);       // [64][40] 5120 B
    unsigned short* tile = (unsigned short*)smem;               // epi: [64][264] 33792 B
    uint4*  offs4 = (uint4*)(smem + 33792);                     // [64] 1024 B
    float4* wts4  = (float4*)(smem + 34816);                    // [64] 1024 B
    float* biasS = (float*)(smem + 35840);                      // 1024 B
    float* redS  = (float*)(smem + 36864);                      // 1024 B
    float* redQ  = (float*)(smem + 37888);                      // 1024 B

    int t = threadIdx.x;
    int n0 = blockIdx.x * 64, bb = blockIdx.y;
    int w = t >> 6, lane = t & 63, quad = lane >> 4, l15 = lane & 15;
    const unsigned short* imb = imgT + (size_t)bb * HW_ * 256;

    // precompute bilinear corners for this block's 64 points
    if (t < 64) {
        float2 g2 = *(const float2*)(pim + (size_t)((size_t)bb * N_ + n0 + t) * 2);
        float x = (g2.x + 1.0f) * (0.5f * W_) - 0.5f;
        float y = (g2.y + 1.0f) * (0.5f * H_) - 0.5f;
        float xf = floorf(x), yf = floorf(y);
        float wx1 = x - xf, wx0 = 1.0f - wx1;
        float wy1 = y - yf, wy0 = 1.0f - wy1;
        int x0 = (int)xf, y0 = (int)yf;
        int x1 = x0 + 1, y1 = y0 + 1;
        float vx0 = (x0 >= 0 && x0 < W_) ? 1.f : 0.f;
        float vx1 = (x1 >= 0 && x1 < W_) ? 1.f : 0.f;
        float vy0 = (y0 >= 0 && y0 < H_) ? 1.f : 0.f;
        float vy1 = (y1 >= 0 && y1 < H_) ? 1.f : 0.f;
        int cx0 = min(max(x0, 0), W_ - 1), cx1 = min(max(x1, 0), W_ - 1);
        int cy0 = min(max(y0, 0), H_ - 1), cy1 = min(max(y1, 0), H_ - 1);
        uint4 o4;
        o4.x = (unsigned)(cy0 * W_ + cx0);
        o4.y = (unsigned)(cy0 * W_ + cx1);
        o4.z = (unsigned)(cy1 * W_ + cx0);
        o4.w = (unsigned)(cy1 * W_ + cx1);
        offs4[t] = o4;
        float4 w4;
        w4.x = wx0 * wy0 * vx0 * vy0;
        w4.y = wx1 * wy0 * vx1 * vy0;
        w4.z = wx0 * wy1 * vx0 * vy1;
        w4.w = wx1 * wy1 * vx1 * vy1;
        wts4[t] = w4;
    }
    biasS[t] = fb[t];

    const f32x4 fzero = {0.f, 0.f, 0.f, 0.f};
    f32x4 acc[4][4];
#pragma unroll
    for (int i = 0; i < 4; ++i)
#pragma unroll
        for (int j = 0; j < 4; ++j) acc[i][j] = fzero;

    for (int kt = 0; kt < 16; ++kt) {
        int k0 = kt * 32;
        __syncthreads();
        // A staging: WfB [256][512] rows m, async 16 B/lane, 4 issues
#pragma unroll
        for (int q = 0; q < 4; ++q) {
            int row = q * 64 + (t >> 2);
            async_copy16(At + (size_t)q * 2048 + (size_t)t * 8,
                         WfB + (size_t)row * K_ + k0 + (t & 3) * 8);
        }
        if (kt < 8) {
            // B staging, img half: gather+blend 8 ch per task (1 pass, 64 pts)
            int pt = t >> 2, cg = t & 3;
            uint4 o4 = offs4[pt];
            float4 w4 = wts4[pt];
            int ch = k0 + cg * 8;
            uint4 cA = *(const uint4*)(imb + (size_t)o4.x * 256 + ch);
            uint4 cB = *(const uint4*)(imb + (size_t)o4.y * 256 + ch);
            uint4 cC = *(const uint4*)(imb + (size_t)o4.z * 256 + ch);
            uint4 cD = *(const uint4*)(imb + (size_t)o4.w * 256 + ch);
            const unsigned short* pa = (const unsigned short*)&cA;
            const unsigned short* pb = (const unsigned short*)&cB;
            const unsigned short* pc = (const unsigned short*)&cC;
            const unsigned short* pd = (const unsigned short*)&cD;
            uint4 ov;
            unsigned short* po = (unsigned short*)&ov;
#pragma unroll
            for (int e = 0; e < 8; ++e)
                po[e] = f2bf(w4.x * bf2f(pa[e]) + w4.y * bf2f(pb[e]) +
                             w4.z * bf2f(pc[e]) + w4.w * bf2f(pd[e]));
            *(uint4*)(Bt + pt * 40 + cg * 8) = ov;
        } else {
            // B staging, pts half: fp32 coalesced load + LDS transpose
            int c_local = t & 31, g = t >> 5;
            int c = (kt - 8) * 32 + c_local;
            const float* src = pts + ((size_t)bb * 256 + c) * (size_t)N_ + n0 + g * 8;
            float4 v0 = *(const float4*)(src + 0);
            float4 v1 = *(const float4*)(src + 4);
            unsigned short* dst = Bt + (size_t)(g * 8) * 40 + c_local;
            dst[0 * 40] = f2bf(v0.x); dst[1 * 40] = f2bf(v0.y);
            dst[2 * 40] = f2bf(v0.z); dst[3 * 40] = f2bf(v0.w);
            dst[4 * 40] = f2bf(v1.x); dst[5 * 40] = f2bf(v1.y);
            dst[6 * 40] = f2bf(v1.z); dst[7 * 40] = f2bf(v1.w);
        }
        __syncthreads();
        bf16x8 af[4], bv[4];
#pragma unroll
        for (int j = 0; j < 4; ++j)
            bv[j] = *(const bf16x8*)(Bt + (j * 16 + l15) * 40 + quad * 8);
#pragma unroll
        for (int i = 0; i < 4; ++i)
            af[i] = *(const bf16x8*)(At + (w * 64 + i * 16 + l15) * 32 + quad * 8);
#pragma unroll
        for (int i = 0; i < 4; ++i)
#pragma unroll
            for (int j = 0; j < 4; ++j)
                acc[i][j] = __builtin_amdgcn_mfma_f32_16x16x32_bf16(af[i], bv[j], acc[i][j], 0, 0, 0);
    }

    // ---- epilogue: bias, BN stats, LDS-tiled coalesced Y stores
    __syncthreads();
#pragma unroll
    for (int i = 0; i < 4; ++i) {
        int mloc = w * 64 + i * 16 + quad * 4;
        float b0 = biasS[mloc + 0], b1 = biasS[mloc + 1];
        float b2 = biasS[mloc + 2], b3 = biasS[mloc + 3];
        float s0 = 0.f, q0 = 0.f, s1 = 0.f, q1 = 0.f;
        float s2 = 0.f, q2 = 0.f, s3 = 0.f, q3 = 0.f;
#pragma unroll
        for (int j = 0; j < 4; ++j) {
            int n = j * 16 + l15;
            float y0 = acc[i][j][0] + b0;
            float y1 = acc[i][j][1] + b1;
            float y2 = acc[i][j][2] + b2;
            float y3 = acc[i][j][3] + b3;
            s0 += y0; q0 += y0 * y0;
            s1 += y1; q1 += y1 * y1;
            s2 += y2; q2 += y2 * y2;
            s3 += y3; q3 += y3 * y3;
            ushort4 o;
            o.x = f2bf(y0); o.y = f2bf(y1); o.z = f2bf(y2); o.w = f2bf(y3);
            *(ushort4*)(tile + n * 264 + mloc) = o;
        }
#pragma unroll
        for (int d = 1; d < 16; d <<= 1) {
            s0 += __shfl_xor(s0, d, 64); q0 += __shfl_xor(q0, d, 64);
            s1 += __shfl_xor(s1, d, 64); q1 += __shfl_xor(q1, d, 64);
            s2 += __shfl_xor(s2, d, 64); q2 += __shfl_xor(q2, d, 64);
            s3 += __shfl_xor(s3, d, 64); q3 += __shfl_xor(q3, d, 64);
        }
        if (l15 == 0) {
            redS[mloc + 0] = s0; redQ[mloc + 0] = q0;
            redS[mloc + 1] = s1; redQ[mloc + 1] = q1;
            redS[mloc + 2] = s2; redQ[mloc + 2] = q2;
            redS[mloc + 3] = s3; redQ[mloc + 3] = q3;
        }
    }
    __syncthreads();
    {
        float* bk = buckets + (size_t)(blockIdx.x & 15) * 512;
        atomicAdd(bk + t, redS[t]);
        atomicAdd(bk + 256 + t, redQ[t]);
    }
    size_t Yrow0 = ((size_t)bb * N_ + n0) * 256;
#pragma unroll
    for (int pass = 0; pass < 8; ++pass) {
        int row = pass * 8 + (t >> 5);
        int col = (t & 31) * 8;
        *(uint4*)(Y + Yrow0 + (size_t)row * 256 + col) = *(const uint4*)(tile + row * 264 + col);
    }
}

// ---- fused gate (unchanged from R0)
__global__ __launch_bounds__(256, 2) void k_gate(const unsigned short* __restrict__ Y,
                                                 const float* __restrict__ buckets,
                                                 const float* __restrict__ gamma,
                                                 const float* __restrict__ beta,
                                                 const unsigned short* __restrict__ saB,
                                                 const float* __restrict__ sab,
                                                 const unsigned short* __restrict__ c1B,
                                                 const float* __restrict__ c1b,
                                                 const unsigned short* __restrict__ c2B,
                                                 unsigned int* __restrict__ camax,
                                                 float* __restrict__ sp_g,
                                                 float* __restrict__ ss_out) {
    __shared__ __align__(16) unsigned short Ft[64 * 264];
    __shared__ __align__(16) unsigned short Ht[64 * 72];
    __shared__ float scS[256], shS[256];
    __shared__ float saPart[4][64];
    __shared__ float spL[64];
    int t = threadIdx.x;
    size_t pts0 = (size_t)blockIdx.x * 64;
    int b = (int)(pts0 >> 14);
    int w = t >> 6, lane = t & 63, quad = lane >> 4, l15 = lane & 15;
    int jrow = w * 16 + l15;

    bf16x8 bvs[8], bvc[8];
#pragma unroll
    for (int kt = 0; kt < 8; ++kt) {
        bvs[kt] = *(const bf16x8*)(saB + (size_t)jrow * 256 + kt * 32 + quad * 8);
        bvc[kt] = *(const bf16x8*)(c1B + (size_t)jrow * 256 + kt * 32 + quad * 8);
    }
    float sbias = sab[jrow];
    float cbias = c1b[jrow];

    {
        float s = 0.f, q = 0.f;
#pragma unroll
        for (int bk = 0; bk < 16; ++bk) {
            s += buckets[bk * 512 + t];
            q += buckets[bk * 512 + 256 + t];
        }
        const float inv = 1.0f / (float)(B_ * N_);
        float mean = s * inv;
        float var = q * inv - mean * mean;
        float sc = gamma[t] * rsqrtf(var + 1e-5f);
        float sh = beta[t] - mean * sc;
        scS[t] = sc;
        shS[t] = sh;
        if (blockIdx.x == 0) { ss_out[t] = sc; ss_out[256 + t] = sh; }
    }
    __syncthreads();

    int cc = (t * 8) & 255;
    float scr[8], shr[8];
#pragma unroll
    for (int e = 0; e < 8; ++e) { scr[e] = scS[cc + e]; shr[e] = shS[cc + e]; }
    for (int idx = t * 8; idx < 64 * 256; idx += 2048) {
        int r = idx >> 8;
        uint4 v = *(const uint4*)(Y + (pts0 + r) * 256 + cc);
        unsigned short* us = (unsigned short*)&v;
#pragma unroll
        for (int e = 0; e < 8; ++e) {
            float f = bf2f(us[e]) * scr[e] + shr[e];
            us[e] = f2bf(fmaxf(f, 0.f));
        }
        *(uint4*)(Ft + r * 264 + cc) = v;
    }
    __syncthreads();

    const f32x4 fzero = {0.f, 0.f, 0.f, 0.f};
    f32x4 accS[4], accC[4];
#pragma unroll
    for (int i = 0; i < 4; ++i) { accS[i] = fzero; accC[i] = fzero; }
#pragma unroll
    for (int kt = 0; kt < 8; ++kt) {
        bf16x8 af[4];
#pragma unroll
        for (int i = 0; i < 4; ++i)
            af[i] = *(const bf16x8*)(Ft + (i * 16 + l15) * 264 + kt * 32 + quad * 8);
#pragma unroll
        for (int i = 0; i < 4; ++i) {
            accS[i] = __builtin_amdgcn_mfma_f32_16x16x32_bf16(af[i], bvs[kt], accS[i], 0, 0, 0);
            accC[i] = __builtin_amdgcn_mfma_f32_16x16x32_bf16(af[i], bvc[kt], accC[i], 0, 0, 0);
        }
    }
#pragma unroll
    for (int i = 0; i < 4; ++i) {
#pragma unroll
        for (int r = 0; r < 4; ++r) {
            float v = accS[i][r] + sbias;
#pragma unroll
            for (int d = 1; d < 16; d <<= 1) v = fmaxf(v, __shfl_xor(v, d, 64));
            if (l15 == 0) saPart[w][i * 16 + quad * 4 + r] = v;
        }
    }
    __syncthreads();
    if (t < 64) {
        float m4 = fmaxf(fmaxf(saPart[0][t], saPart[1][t]),
                         fmaxf(saPart[2][t], saPart[3][t]));
        float sv = 1.0f / (1.0f + __expf(-m4));
        spL[t] = sv;
        sp_g[pts0 + t] = sv;
    }
    __syncthreads();

#pragma unroll
    for (int i = 0; i < 4; ++i) {
#pragma unroll
        for (int r = 0; r < 4; ++r) {
            int pt = i * 16 + quad * 4 + r;
            float hv = fmaxf(accC[i][r] * spL[pt] + cbias, 0.f);
            Ht[pt * 72 + jrow] = f2bf(hv);
        }
    }
    __syncthreads();

    {
        bf16x8 b2a[4], b2b[4];
#pragma unroll
        for (int mt = 0; mt < 4; ++mt) {
            b2a[mt] = *(const bf16x8*)(c2B + (size_t)(w * 64 + mt * 16 + l15) * 64 + quad * 8);
            b2b[mt] = *(const bf16x8*)(c2B + (size_t)(w * 64 + mt * 16 + l15) * 64 + 32 + quad * 8);
        }
        float vmax[4] = {-3e38f, -3e38f, -3e38f, -3e38f};
#pragma unroll
        for (int i = 0; i < 4; ++i) {
            bf16x8 a0 = *(const bf16x8*)(Ht + (i * 16 + l15) * 72 + quad * 8);
            bf16x8 a1 = *(const bf16x8*)(Ht + (i * 16 + l15) * 72 + 32 + quad * 8);
#pragma unroll
            for (int mt = 0; mt < 4; ++mt) {
                f32x4 acc = __builtin_amdgcn_mfma_f32_16x16x32_bf16(a0, b2a[mt], fzero, 0, 0, 0);
                acc = __builtin_amdgcn_mfma_f32_16x16x32_bf16(a1, b2b[mt], acc, 0, 0, 0);
#pragma unroll
                for (int r = 0; r < 4; ++r) vmax[mt] = fmaxf(vmax[mt], acc[r]);
            }
        }
        unsigned int* cam = camax + (size_t)(blockIdx.x & 7) * 1024 + b * 256;
#pragma unroll
        for (int mt = 0; mt < 4; ++mt) {
            float v = vmax[mt];
            v = fmaxf(v, __shfl_xor(v, 16, 64));
            v = fmaxf(v, __shfl_xor(v, 32, 64));
            if (quad == 0) atomicMax(cam + w * 64 + mt * 16 + l15, fkey(v));
        }
    }
}

// ---- out (unchanged from R0)
__global__ __launch_bounds__(256) void k_out(const unsigned short* __restrict__ Y,
                                             const unsigned int* __restrict__ camax,
                                             const float* __restrict__ c2b,
                                             const float* __restrict__ ss,
                                             const float* __restrict__ sp_g,
                                             float* __restrict__ out) {
    __shared__ __align__(16) unsigned short tile[64 * 68];
    __shared__ float ch[64], scT[64], shT[64], spT[64];
    int t = threadIdx.x;
    int n0 = blockIdx.x * 64, m0 = blockIdx.y * 64, b = blockIdx.z;
    if (t < 64) {
        int m = m0 + t;
        unsigned int k = 0u;
#pragma unroll
        for (int bk = 0; bk < 8; ++bk) k = max(k, camax[bk * 1024 + b * 256 + m]);
        ch[t] = 1.0f / (1.0f + __expf(-(funkey(k) + c2b[m])));
        scT[t] = ss[m];
        shT[t] = ss[256 + m];
        spT[t] = sp_g[(size_t)b * N_ + n0 + t];
    }
    int sub = (t & 15) * 4, grp = t >> 4;
    const unsigned short* src = Y + ((size_t)b * N_ + n0) * 256 + m0;
#pragma unroll
    for (int it = 0; it < 4; ++it) {
        int nl = grp + it * 16;
        ushort4 v = *(const ushort4*)(src + (size_t)nl * 256 + sub);
        *(ushort4*)(tile + nl * 68 + sub) = v;
    }
    __syncthreads();
    float* dst = out + ((size_t)b * 256 + m0) * N_ + n0;
#pragma unroll
    for (int it = 0; it < 4; ++it) {
        int ml = grp + it * 16;
        float g = ch[ml], scv = scT[ml], shv = shT[ml];
        float4 o;
        o.x = fmaxf(bf2f(tile[(sub + 0) * 68 + ml]) * scv + shv, 0.f) * spT[sub + 0] * g;
        o.y = fmaxf(bf2f(tile[(sub + 1) * 68 + ml]) * scv + shv, 0.f) * spT[sub + 1] * g;
        o.z = fmaxf(bf2f(tile[(sub + 2) * 68 + ml]) * scv + shv, 0.f) * spT[sub + 2] * g;
        o.w = fmaxf(bf2f(tile[(sub + 3) * 68 + ml]) * scv + shv, 0.f) * spT[sub + 3] * g;
        *(float4*)(dst + (size_t)ml * N_ + sub) = o;
    }
}

extern "C" void kernel_launch(void* const* d_in, const int* in_sizes, int n_in,
                              void* d_out, int out_size, void* d_ws, size_t ws_size,
                              hipStream_t stream) {
    (void)in_sizes; (void)n_in; (void)out_size; (void)ws_size;
    const float* pts_img = (const float*)d_in[0];
    const float* img     = (const float*)d_in[1];
    const float* pts     = (const float*)d_in[2];
    const float* fw      = (const float*)d_in[3];
    const float* fbias   = (const float*)d_in[4];
    const float* gamma   = (const float*)d_in[5];
    const float* beta    = (const float*)d_in[6];
    const float* c1w     = (const float*)d_in[7];
    const float* c1b     = (const float*)d_in[8];
    const float* c2w     = (const float*)d_in[9];
    const float* c2b     = (const float*)d_in[10];
    const float* saw     = (const float*)d_in[11];
    const float* sab     = (const float*)d_in[12];
    float* out = (float*)d_out;

    char* ws = (char*)d_ws;
    unsigned short* imgT = (unsigned short*)(ws);              // 20,971,520 B
    unsigned short* Y    = (unsigned short*)(ws + 20971520);   // 33,554,432 B
    unsigned short* WfB  = (unsigned short*)(ws + 54525952);   // 262,144 B
    unsigned short* saB  = (unsigned short*)(ws + 54788096);   // 32,768 B
    unsigned short* ca1B = (unsigned short*)(ws + 54820864);   // 32,768 B
    unsigned short* ca2B = (unsigned short*)(ws + 54853632);   // 32,768 B
    float* buckets       = (float*)(ws + 54886400);            // 32,768 B
    unsigned int* camax  = (unsigned int*)(ws + 54919168);     // 32,768 B
    float* sp_g          = (float*)(ws + 54951936);            // 262,144 B
    float* ss            = (float*)(ws + 55214080);            // 2,048 B

    k_imgt<<<3264, 256, 0, stream>>>(img, imgT, fw, saw, c1w, c2w,
                                     WfB, saB, ca1B, ca2B, buckets, camax);
    k_gemm1f<<<dim3(256, 4), 256, 0, stream>>>(WfB, pts_img, imgT, pts, fbias, Y, buckets);
    k_gate<<<1024, 256, 0, stream>>>(Y, buckets, gamma, beta, saB, sab, ca1B, c1b,
                                     ca2B, camax, sp_g, ss);
    k_out<<<dim3(256, 4, 4), 256, 0, stream>>>(Y, camax, c2b, ss, sp_g, out);
}